// Round 4
// baseline (174.618 us; speedup 1.0000x reference)
//
#include <hip/hip_runtime.h>

// ---------------------------------------------------------------------------
// RelativeSelfMultiheadAttn (Transformer-XL style) on gfx950.
// T=2048, B=2, D=512, NH=8, HD=64.
// Pipeline: prep -> gemm01 (QKV+R) -> attn (split-k flash) -> combine -> gemmO.
// Round-4: flash-decoding split-k (1280 equal chunks of <=8 k-tiles, partial
// m/l/O + combine pass), bf16 G-scratch -> 49.7KB LDS -> 3 blocks/CU,
// coalesced vT store via LDS transpose in gemm01 epilogue.
// ---------------------------------------------------------------------------

typedef float f32x4 __attribute__((ext_vector_type(4)));
typedef short bf16x8 __attribute__((ext_vector_type(8)));

#define NW 1314304
#define OFF_INB  1310720
#define OFF_INW  0
#define OFF_OUTW 786432
#define OFF_POSW 1048576
// bias-buffer local offsets (floats)
#define BB_IN  0
#define BB_OUT 1536
#define BB_POS 2048
#define BB_RW  2560
#define BB_RR  3072

#define L2E 1.44269504088896340736f

__device__ __forceinline__ unsigned short f2bf(float x) {
  unsigned u = __builtin_bit_cast(unsigned, x);
  u += 0x7fffu + ((u >> 16) & 1u);   // RNE
  return (unsigned short)(u >> 16);
}
__device__ __forceinline__ float bf2f(unsigned short s) {
  return __builtin_bit_cast(float, ((unsigned)s) << 16);
}
__device__ __forceinline__ unsigned pk2(float lo, float hi) {
  return (unsigned)f2bf(lo) | ((unsigned)f2bf(hi) << 16);
}

// ---------------- prep: weight sample + activation bf16 cast ---------------
__global__ void prep_kernel(const float* __restrict__ mu, const float* __restrict__ rho,
                            const float* __restrict__ eps,
                            const float* __restrict__ input, const float* __restrict__ pos,
                            unsigned short* __restrict__ Wh, float* __restrict__ Bf,
                            unsigned short* __restrict__ inH, unsigned short* __restrict__ posH) {
  const int bx = blockIdx.x;
  if (bx < 1284) {
    int i = (bx * 256 + threadIdx.x) * 4;
    if (i < NW) {
      float4 m = *(const float4*)&mu[i];
      float4 r = *(const float4*)&rho[i];
      float4 e = *(const float4*)&eps[i];
      float w0 = m.x + ((r.x > 20.f) ? r.x : log1pf(expf(r.x))) * e.x;
      float w1 = m.y + ((r.y > 20.f) ? r.y : log1pf(expf(r.y))) * e.y;
      float w2 = m.z + ((r.z > 20.f) ? r.z : log1pf(expf(r.z))) * e.z;
      float w3 = m.w + ((r.w > 20.f) ? r.w : log1pf(expf(r.w))) * e.w;
      union { unsigned short s[4]; uint2 u; } p;
      p.s[0] = f2bf(w0); p.s[1] = f2bf(w1); p.s[2] = f2bf(w2); p.s[3] = f2bf(w3);
      *(uint2*)&Wh[i] = p.u;
      if (i >= OFF_INB) {
        float4 b; b.x = w0; b.y = w1; b.z = w2; b.w = w3;
        *(float4*)&Bf[i - OFF_INB] = b;
      }
    }
  } else if (bx < 3332) {
    int i = ((bx - 1284) * 256 + threadIdx.x) * 4;
    float4 v = *(const float4*)&input[i];
    union { unsigned short s[4]; uint2 u; } p;
    p.s[0] = f2bf(v.x); p.s[1] = f2bf(v.y); p.s[2] = f2bf(v.z); p.s[3] = f2bf(v.w);
    *(uint2*)&inH[i] = p.u;
  } else {
    int i = ((bx - 3332) * 256 + threadIdx.x) * 4;
    float4 v = *(const float4*)&pos[i];
    union { unsigned short s[4]; uint2 u; } p;
    p.s[0] = f2bf(v.x); p.s[1] = f2bf(v.y); p.s[2] = f2bf(v.z); p.s[3] = f2bf(v.w);
    *(uint2*)&posH[i] = p.u;
  }
}

// ---------------- shared 64x64x512 bf16 tile core (C = A * W^T) ------------
__device__ __forceinline__ void gemm_loop(const unsigned short* __restrict__ A,
                                          const unsigned short* __restrict__ B,
                                          unsigned short* As, unsigned short* Bs,
                                          f32x4 (&acc)[4]) {
  const int tid = threadIdx.x;
  const int wv = tid >> 6, lane = tid & 63, g = lane >> 4, cc = lane & 15;
  const int row = tid >> 2, q4 = tid & 3;
  const unsigned short* Ap = A + (size_t)row * 512 + 16 * q4;
  const unsigned short* Bp = B + (size_t)row * 512 + 16 * q4;

  *(uint4*)&As[row * 72 + 16 * q4]     = *(const uint4*)Ap;
  *(uint4*)&As[row * 72 + 16 * q4 + 8] = *(const uint4*)(Ap + 8);
  *(uint4*)&Bs[row * 72 + 16 * q4]     = *(const uint4*)Bp;
  *(uint4*)&Bs[row * 72 + 16 * q4 + 8] = *(const uint4*)(Bp + 8);
  __syncthreads();

  for (int it = 0; it < 8; it++) {
    uint4 a0, a1, b0, b1;
    const bool pf = (it < 7);
    if (pf) {
      const unsigned short* An = Ap + 64 * (it + 1);
      const unsigned short* Bn = Bp + 64 * (it + 1);
      a0 = *(const uint4*)An; a1 = *(const uint4*)(An + 8);
      b0 = *(const uint4*)Bn; b1 = *(const uint4*)(Bn + 8);
    }
    __builtin_amdgcn_s_setprio(1);
#pragma unroll
    for (int ks = 0; ks < 2; ks++) {
      bf16x8 af = *(const bf16x8*)&As[(16 * wv + cc) * 72 + 32 * ks + 8 * g];
#pragma unroll
      for (int fn = 0; fn < 4; fn++) {
        bf16x8 bf = *(const bf16x8*)&Bs[(16 * fn + cc) * 72 + 32 * ks + 8 * g];
        acc[fn] = __builtin_amdgcn_mfma_f32_16x16x32_bf16(af, bf, acc[fn], 0, 0, 0);
      }
    }
    __builtin_amdgcn_s_setprio(0);
    __syncthreads();
    if (pf) {
      *(uint4*)&As[row * 72 + 16 * q4]     = a0;
      *(uint4*)&As[row * 72 + 16 * q4 + 8] = a1;
      *(uint4*)&Bs[row * 72 + 16 * q4]     = b0;
      *(uint4*)&Bs[row * 72 + 16 * q4 + 8] = b1;
    }
    __syncthreads();
  }
}

// ---------------- gemm01: QKV projection (1536 blocks) + R proj (256) ------
__global__ __launch_bounds__(256, 2)
void gemm01_kernel(const unsigned short* __restrict__ inH, const unsigned short* __restrict__ posH,
                   const unsigned short* __restrict__ Wh, const float* __restrict__ Bf,
                   unsigned short* __restrict__ qrw, unsigned short* __restrict__ qrr,
                   unsigned short* __restrict__ kbuf, unsigned short* __restrict__ vT,
                   unsigned short* __restrict__ rbuf) {
  __shared__ __align__(16) unsigned short As[64 * 72];
  __shared__ __align__(16) unsigned short Bs[64 * 72];
  const int bx = blockIdx.x;
  const int tid = threadIdx.x;
  const int wv = tid >> 6, lane = tid & 63, g = lane >> 4, cc = lane & 15;

  const bool isR = (bx >= 1536);
  int m0, n0;
  const unsigned short *A, *W;
  if (!isR) {
    m0 = (bx & 63) << 6; n0 = (bx >> 6) << 6;
    A = inH + (size_t)m0 * 512;  W = Wh + OFF_INW + (size_t)n0 * 512;
  } else {
    const int t = bx - 1536;
    m0 = (t & 31) << 6; n0 = (t >> 5) << 6;
    A = posH + (size_t)m0 * 512; W = Wh + OFF_POSW + (size_t)n0 * 512;
  }

  f32x4 acc[4];
#pragma unroll
  for (int i = 0; i < 4; i++) { acc[i][0] = 0.f; acc[i][1] = 0.f; acc[i][2] = 0.f; acc[i][3] = 0.f; }
  gemm_loop(A, W, As, Bs, acc);

  const int sec = n0 >> 9;   // uniform per block (QKV part)
  if (!isR && sec == 2) {
    // ---- V: stage C tile (bf16, +bias) in As, then coalesced vT store ----
#pragma unroll
    for (int fn = 0; fn < 4; fn++) {
      const int col = n0 + 16 * fn + cc;
#pragma unroll
      for (int r = 0; r < 4; r++)
        As[(16 * wv + 4 * g + r) * 72 + 16 * fn + cc] = f2bf(acc[fn][r] + Bf[BB_IN + col]);
    }
    __syncthreads();
    const int nh2 = (n0 >> 6) & 7;
#pragma unroll
    for (int cpass = 0; cpass < 2; cpass++) {
      const int ch = tid + cpass * 256;            // 512 chunks of 8 t-values
      const int ncol = ch >> 3, bb2 = (ch >> 2) & 1, jc = ch & 3;
      union { unsigned short s[8]; uint4 u; } pk;
#pragma unroll
      for (int jj = 0; jj < 8; jj++)
        pk.s[jj] = As[(2 * (8 * jc + jj) + bb2) * 72 + ncol];
      *(uint4*)&vT[((size_t)(bb2 * 8 + nh2) * 64 + ncol) * 2048 + (m0 >> 1) + 8 * jc] = pk.u;
    }
    return;
  }

#pragma unroll
  for (int fn = 0; fn < 4; fn++) {
    const int col = n0 + 16 * fn + cc;
#pragma unroll
    for (int r = 0; r < 4; r++) {
      const int mrow = m0 + 16 * wv + 4 * g + r;
      float v = acc[fn][r];
      if (!isR) {
        v += Bf[BB_IN + col];
        const int d = col & 511;
        const int nh = d >> 6, hd = d & 63;
        const int t = mrow >> 1, bb = mrow & 1;
        const size_t bi = ((size_t)(bb * 8 + nh) * 2048 + t) * 64 + hd;
        if (sec == 0) {
          qrw[bi] = f2bf(v + Bf[BB_RW + d]);
          qrr[bi] = f2bf(v + Bf[BB_RR + d]);
        } else {
          kbuf[bi] = f2bf(v);
        }
      } else {
        v += Bf[BB_POS + col];
        rbuf[((size_t)(col >> 6) * 2048 + mrow) * 64 + (col & 63)] = f2bf(v);
      }
    }
  }
}

// ---------------- gemmO: out projection -> f32 d_out -----------------------
__global__ __launch_bounds__(256, 2)
void gemmO_kernel(const unsigned short* __restrict__ av, const unsigned short* __restrict__ W,
                  const float* __restrict__ Bf, float* __restrict__ outp) {
  __shared__ __align__(16) unsigned short As[64 * 72];
  __shared__ __align__(16) unsigned short Bs[64 * 72];
  const int bx = blockIdx.x;
  const int tid = threadIdx.x;
  const int wv = tid >> 6, lane = tid & 63, g = lane >> 4, cc = lane & 15;
  const int m0 = (bx & 63) << 6, n0 = (bx >> 6) << 6;

  f32x4 acc[4];
#pragma unroll
  for (int i = 0; i < 4; i++) { acc[i][0] = 0.f; acc[i][1] = 0.f; acc[i][2] = 0.f; acc[i][3] = 0.f; }
  gemm_loop(av + (size_t)m0 * 512, W + (size_t)n0 * 512, As, Bs, acc);

#pragma unroll
  for (int fn = 0; fn < 4; fn++) {
    const int col = n0 + 16 * fn + cc;
#pragma unroll
    for (int r = 0; r < 4; r++) {
      const int mrow = m0 + 16 * wv + 4 * g + r;
      outp[(size_t)mrow * 512 + col] = acc[fn][r] + Bf[BB_OUT + col];
    }
  }
}

// ---------------- split-k fused relative flash attention -------------------
// 1280 blocks: bx -> bn = bx&15, sid = 79-(bx>>4) (big-qt chunks first).
// sid -> (qt, split s, nsplit): chunks of <=8 k-tiles -> equal-size blocks.
// 3 blocks/CU (49.7KB LDS). Partial (m,l,O-bf16) for nsplit>1; direct store
// for qt<=7. Swapped St = K*Q^T softmax; BD band-GEMM on R ring buffer; T14.
__global__ __launch_bounds__(256, 3)
void attn_kernel(const unsigned short* __restrict__ qrw, const unsigned short* __restrict__ qrr,
                 const unsigned short* __restrict__ kb, const unsigned short* __restrict__ vt,
                 const unsigned short* __restrict__ rb, unsigned short* __restrict__ av,
                 unsigned short* __restrict__ pO, float* __restrict__ pStats)
{
  __shared__ __align__(16) unsigned short Ks[64 * 72];
  __shared__ __align__(16) unsigned short Vs[64 * 72];
  __shared__ __align__(16) unsigned short Rs[128 * 72];   // ring: slot = u & 127
  __shared__ __align__(16) unsigned short Gs[4 * 80 * 20]; // per-wave [80][20] bf16

  const int tid = threadIdx.x;
  const int wv = tid >> 6, lane = tid & 63, g = lane >> 4, cc = lane & 15;
  const int bx = (int)blockIdx.x;
  const int bn = bx & 15;
  const int sid = 79 - (bx >> 4);
  int qt, s, ns;
  if (sid < 8)       { qt = sid;                s = 0;           ns = 1; }
  else if (sid < 24) { qt = 8 + ((sid - 8) >> 1); s = (sid - 8) & 1; ns = 2; }
  else if (sid < 48) { const int t = sid - 24; const int q3 = t / 3; qt = 16 + q3; s = t - 3 * q3; ns = 3; }
  else               { const int t = sid - 48; qt = 24 + (t >> 2); s = t & 3; ns = 4; }
  const int kt0 = s * 8;
  const int kt1 = (kt0 + 8 < qt + 1) ? (kt0 + 8) : (qt + 1);

  const int nh = bn & 7, bb = bn >> 3;
  const int i0 = qt * 64;
  const int i0g = i0 + wv * 16;
  const int w0base = 1984 - i0;                // R window base at kt=0

  const size_t qko = (size_t)bn * 2048 * 64;
  const size_t ro = (size_t)nh * 2048 * 64;

  // hoisted Q fragments (B-operand: lane holds Q[i0g+cc][d-slice])
  bf16x8 qw[2], qr[2];
#pragma unroll
  for (int ks = 0; ks < 2; ks++) {
    qw[ks] = *(const bf16x8*)&qrw[qko + (size_t)(i0g + cc) * 64 + 32 * ks + 8 * g];
    qr[ks] = *(const bf16x8*)&qrr[qko + (size_t)(i0g + cc) * 64 + 32 * ks + 8 * g];
  }

  float m_run = -3.0e38f, l_run = 0.f;
  f32x4 o[4];
#pragma unroll
  for (int i = 0; i < 4; i++) { o[i][0] = 0.f; o[i][1] = 0.f; o[i][2] = 0.f; o[i][3] = 0.f; }

  const int srow = tid >> 2, sq = tid & 3;     // K/V/R-loop: 4 thr/row, 16 shorts
  const int rrow = tid >> 1, rhalf = tid & 1;  // R prologue: 2 thr/row, 32 shorts
  unsigned short* Gw = &Gs[wv * 1600];
  const int rbase = 48 - 16 * wv;

  // ---- prologue: stage kt0 K/V tile + 128-row R window ----
  {
    const unsigned short* kp = &kb[qko + (size_t)(kt0 * 64 + srow) * 64 + 16 * sq];
    *(uint4*)&Ks[srow * 72 + 16 * sq]     = *(const uint4*)kp;
    *(uint4*)&Ks[srow * 72 + 16 * sq + 8] = *(const uint4*)(kp + 8);
    const unsigned short* vp = &vt[qko + (size_t)srow * 2048 + kt0 * 64 + 16 * sq];
    *(uint4*)&Vs[srow * 72 + 16 * sq]     = *(const uint4*)vp;
    *(uint4*)&Vs[srow * 72 + 16 * sq + 8] = *(const uint4*)(vp + 8);
    const int u0 = w0base + kt0 * 64 + rrow;
    const int uc0 = u0 > 2047 ? 2047 : u0;     // clamped rows only feed masked entries
    const unsigned short* rp = &rb[ro + (size_t)uc0 * 64 + 32 * rhalf];
    unsigned short* rd = &Rs[(u0 & 127) * 72 + 32 * rhalf];
    *(uint4*)rd        = *(const uint4*)rp;
    *(uint4*)(rd + 8)  = *(const uint4*)(rp + 8);
    *(uint4*)(rd + 16) = *(const uint4*)(rp + 16);
    *(uint4*)(rd + 24) = *(const uint4*)(rp + 24);
  }
  __syncthreads();

  for (int kt = kt0; kt < kt1; kt++) {
    const int j0 = kt * 64;
    const int w0k = w0base + j0;
    const bool pf = (kt + 1 < kt1);

    // ---- T14: issue kt+1 loads into regs (latency hides under compute) ----
    uint4 ka0, ka1, va0, va1, ra0, ra1;
    int rslot = 0;
    if (pf) {
      const unsigned short* kp = &kb[qko + (size_t)(j0 + 64 + srow) * 64 + 16 * sq];
      ka0 = *(const uint4*)kp; ka1 = *(const uint4*)(kp + 8);
      const unsigned short* vp = &vt[qko + (size_t)srow * 2048 + j0 + 64 + 16 * sq];
      va0 = *(const uint4*)vp; va1 = *(const uint4*)(vp + 8);
      const int unew = w0k + 128 + (tid >> 2);  // 64 new ring rows
      rslot = unew & 127;
      const int uc = unew > 2047 ? 2047 : unew;
      const unsigned short* rp = &rb[ro + (size_t)uc * 64 + 16 * sq];
      ra0 = *(const uint4*)rp; ra1 = *(const uint4*)(rp + 8);
    }

    // ---- St[jj,ii] = sum_d K[j0+jj,d] * Qrw[i0g+ii,d] ----
    f32x4 st[4];
#pragma unroll
    for (int i = 0; i < 4; i++) { st[i][0] = 0.f; st[i][1] = 0.f; st[i][2] = 0.f; st[i][3] = 0.f; }
    __builtin_amdgcn_s_setprio(1);
#pragma unroll
    for (int ks = 0; ks < 2; ks++) {
#pragma unroll
      for (int fm = 0; fm < 4; fm++) {
        bf16x8 ka = *(const bf16x8*)&Ks[(16 * fm + cc) * 72 + 32 * ks + 8 * g];
        st[fm] = __builtin_amdgcn_mfma_f32_16x16x32_bf16(ka, qw[ks], st[fm], 0, 0, 0);
      }
    }
    // ---- G[c,ii] = sum_d R[ring(w0k+rbase+c),d] * Qrr[i0g+ii,d] ----
    f32x4 gt[5];
#pragma unroll
    for (int i = 0; i < 5; i++) { gt[i][0] = 0.f; gt[i][1] = 0.f; gt[i][2] = 0.f; gt[i][3] = 0.f; }
    const int rr0 = w0k + rbase + cc;
#pragma unroll
    for (int ks = 0; ks < 2; ks++) {
#pragma unroll
      for (int fm = 0; fm < 5; fm++) {
        const int rrw = (rr0 + 16 * fm) & 127;
        bf16x8 ra = *(const bf16x8*)&Rs[rrw * 72 + 32 * ks + 8 * g];
        gt[fm] = __builtin_amdgcn_mfma_f32_16x16x32_bf16(ra, qr[ks], gt[fm], 0, 0, 0);
      }
    }
    __builtin_amdgcn_s_setprio(0);
#pragma unroll
    for (int fm = 0; fm < 5; fm++)
#pragma unroll
      for (int r = 0; r < 4; r++)
        Gw[(16 * fm + 4 * g + r) * 20 + cc] = f2bf(gt[fm][r]);  // bf16, stride 20

    // ---- combine + mask + online softmax (state lives at query ii == cc) ----
    float p[4][4];
    float tm = -3.0e38f;
    const bool diag = (kt == qt);
#pragma unroll
    for (int fm = 0; fm < 4; fm++) {
#pragma unroll
      for (int r = 0; r < 4; r++) {
        const int jj = 16 * fm + 4 * g + r;
        float bd = bf2f(Gw[(jj - cc + 15) * 20 + cc]);     // rel-shift gather
        float sv = (st[fm][r] + bd) * 0.125f;
        if (diag && (jj > cc + 16 * wv)) sv = -3.0e38f;    // causal mask
        p[fm][r] = sv;
        tm = fmaxf(tm, sv);
      }
    }
    tm = fmaxf(tm, __shfl_xor(tm, 16));
    tm = fmaxf(tm, __shfl_xor(tm, 32));
    const float m_new = fmaxf(m_run, tm);
    const float sc = exp2f((m_run - m_new) * L2E);
    float ps = 0.f;
#pragma unroll
    for (int fm = 0; fm < 4; fm++)
#pragma unroll
      for (int r = 0; r < 4; r++) {
        float pv = exp2f((p[fm][r] - m_new) * L2E);
        p[fm][r] = pv;
        ps += pv;
      }
    ps += __shfl_xor(ps, 16);
    ps += __shfl_xor(ps, 32);
    l_run = l_run * sc + ps;
    m_run = m_new;

    // rescale O (O rows are ii = 4g+r; state at lane ii)
    float scr[4];
#pragma unroll
    for (int r = 0; r < 4; r++) scr[r] = __shfl(sc, 4 * g + r);
#pragma unroll
    for (int fn = 0; fn < 4; fn++)
#pragma unroll
      for (int r = 0; r < 4; r++) o[fn][r] *= scr[r];

    // pack P to bf16 pairs and shfl-redistribute into PV A-frags
    unsigned u01[4], u23[4];
#pragma unroll
    for (int fm = 0; fm < 4; fm++) {
      u01[fm] = pk2(p[fm][0], p[fm][1]);
      u23[fm] = pk2(p[fm][2], p[fm][3]);
    }
    bf16x8 pa[2];
#pragma unroll
    for (int ks = 0; ks < 2; ks++) {
      union { unsigned u[4]; bf16x8 v; } pw;
#pragma unroll
      for (int j = 0; j < 4; j++) {
        const int srcl = (2 * (g & 1) + (j >> 1)) * 16 + cc;
        unsigned v0 = __shfl((j & 1) ? u23[2 * ks] : u01[2 * ks], srcl);
        unsigned v1 = __shfl((j & 1) ? u23[2 * ks + 1] : u01[2 * ks + 1], srcl);
        pw.u[j] = (g >> 1) ? v1 : v0;
      }
      pa[ks] = pw.v;
    }
    // ---- O[ii,hd] += P[ii,jj] * V[j0+jj,hd] ----
    __builtin_amdgcn_s_setprio(1);
#pragma unroll
    for (int ks = 0; ks < 2; ks++) {
#pragma unroll
      for (int fn = 0; fn < 4; fn++) {
        bf16x8 vb = *(const bf16x8*)&Vs[(16 * fn + cc) * 72 + 32 * ks + 8 * g];
        o[fn] = __builtin_amdgcn_mfma_f32_16x16x32_bf16(pa[ks], vb, o[fn], 0, 0, 0);
      }
    }
    __builtin_amdgcn_s_setprio(0);

    __syncthreads();           // all waves done reading Ks/Vs/Rs
    if (pf) {
      *(uint4*)&Ks[srow * 72 + 16 * sq]     = ka0;
      *(uint4*)&Ks[srow * 72 + 16 * sq + 8] = ka1;
      *(uint4*)&Vs[srow * 72 + 16 * sq]     = va0;
      *(uint4*)&Vs[srow * 72 + 16 * sq + 8] = va1;
      unsigned short* rd = &Rs[rslot * 72 + 16 * sq];
      *(uint4*)rd       = ra0;
      *(uint4*)(rd + 8) = ra1;
    }
    __syncthreads();           // next tiles ready
  }

  if (ns == 1) {
    // ---- direct: normalize and store attn_vec[t][b][n][hd] (bf16) ----
    const float inv = 1.0f / l_run;
    float invr[4];
#pragma unroll
    for (int r = 0; r < 4; r++) invr[r] = __shfl(inv, 4 * g + r);
#pragma unroll
    for (int fn = 0; fn < 4; fn++) {
      const int hd = 16 * fn + cc;
#pragma unroll
      for (int r = 0; r < 4; r++) {
        const int irow = i0g + 4 * g + r;
        av[((size_t)(irow * 2 + bb) * 8 + nh) * 64 + hd] = f2bf(o[fn][r] * invr[r]);
      }
    }
  } else {
    // ---- partial: unnormalized O (bf16) + per-row (m,l) ----
    const size_t slot = (size_t)(bn * 80 + sid);
#pragma unroll
    for (int fn = 0; fn < 4; fn++) {
      const int hd = 16 * fn + cc;
#pragma unroll
      for (int r = 0; r < 4; r++)
        pO[slot * 4096 + (16 * wv + 4 * g + r) * 64 + hd] = f2bf(o[fn][r]);
    }
    if (g == 0) {
      pStats[slot * 128 + (16 * wv + cc) * 2]     = m_run;
      pStats[slot * 128 + (16 * wv + cc) * 2 + 1] = l_run;
    }
  }
}

// ---------------- combine: merge split-k partials (qt >= 8) ----------------
__global__ __launch_bounds__(256)
void combine_kernel(const unsigned short* __restrict__ pO, const float* __restrict__ pStats,
                    unsigned short* __restrict__ av) {
  const int bxx = (int)blockIdx.x;       // 16 bn x 24 qt
  const int bn = bxx & 15, qt = 8 + (bxx >> 4);
  const int nh = bn & 7, bb = bn >> 3;
  const int ns = (qt >> 3) + 1;
  const int sid0 = (qt < 16) ? (8 + (qt - 8) * 2)
                 : (qt < 24) ? (24 + (qt - 16) * 3)
                             : (48 + (qt - 24) * 4);
  const int tid = threadIdx.x;
  const int ql = tid >> 2, hq = tid & 3;
  const size_t sb = (size_t)(bn * 80 + sid0);

  float M = -3.0e38f;
  for (int i = 0; i < ns; i++)
    M = fmaxf(M, pStats[(sb + i) * 128 + ql * 2]);

  float L = 0.f;
  float accv[16];
#pragma unroll
  for (int j = 0; j < 16; j++) accv[j] = 0.f;
  for (int i = 0; i < ns; i++) {
    const float mi = pStats[(sb + i) * 128 + ql * 2];
    const float li = pStats[(sb + i) * 128 + ql * 2 + 1];
    const float w = exp2f((mi - M) * L2E);
    L += w * li;
    union { uint4 u; unsigned short s[8]; } c0, c1;
    const unsigned short* src = &pO[(sb + i) * 4096 + ql * 64 + 16 * hq];
    c0.u = *(const uint4*)src;
    c1.u = *(const uint4*)(src + 8);
#pragma unroll
    for (int j = 0; j < 8; j++) accv[j]     += w * bf2f(c0.s[j]);
#pragma unroll
    for (int j = 0; j < 8; j++) accv[8 + j] += w * bf2f(c1.s[j]);
  }
  const float inv = 1.0f / L;
  union { uint4 u; unsigned short s[8]; } o0, o1;
#pragma unroll
  for (int j = 0; j < 8; j++) o0.s[j] = f2bf(accv[j] * inv);
#pragma unroll
  for (int j = 0; j < 8; j++) o1.s[j] = f2bf(accv[8 + j] * inv);
  const int q = qt * 64 + ql;
  unsigned short* dst = &av[((size_t)(q * 2 + bb) * 8 + nh) * 64 + 16 * hq];
  *(uint4*)dst       = o0.u;
  *(uint4*)(dst + 8) = o1.u;
}

// ---------------------------------------------------------------------------
extern "C" void kernel_launch(void* const* d_in, const int* in_sizes, int n_in,
                              void* d_out, int out_size, void* d_ws, size_t ws_size,
                              hipStream_t stream) {
  const float* input = (const float*)d_in[0];
  const float* pos   = (const float*)d_in[1];
  // d_in[2] attn_mask: known causal triu(1), not read
  const float* mu  = (const float*)d_in[3];
  const float* rho = (const float*)d_in[4];
  const float* eps = (const float*)d_in[5];
  float* out = (float*)d_out;

  // workspace layout (bytes); total ~39 MB. av aliases inH (dead after gemm01).
  char* ws = (char*)d_ws;
  unsigned short* Wh   = (unsigned short*)ws;                 // 2,628,608
  float*          Bf   = (float*)(ws + 2628608);              // 14,336
  unsigned short* inH  = (unsigned short*)(ws + 2642944);     // 4,194,304
  unsigned short* posH = (unsigned short*)(ws + 6837248);     // 2,097,152
  unsigned short* qrw  = (unsigned short*)(ws + 8934400);     // 4 MB each
  unsigned short* qrr  = (unsigned short*)(ws + 13128704);
  unsigned short* kbuf = (unsigned short*)(ws + 17323008);
  unsigned short* vT   = (unsigned short*)(ws + 21517312);
  unsigned short* rbuf = (unsigned short*)(ws + 25711616);    // 2,097,152
  unsigned short* pO   = (unsigned short*)(ws + 27808768);    // 10,485,760
  float*          pSt  = (float*)(ws + 38294528);             // 655,360
  unsigned short* av   = inH;                                 // alias

  prep_kernel<<<dim3(4356), dim3(256), 0, stream>>>(mu, rho, eps, input, pos, Wh, Bf, inH, posH);
  gemm01_kernel<<<dim3(1792), dim3(256), 0, stream>>>(inH, posH, Wh, Bf, qrw, qrr, kbuf, vT, rbuf);
  attn_kernel<<<dim3(1280), dim3(256), 0, stream>>>(qrw, qrr, kbuf, vT, rbuf, av, pO, pSt);
  combine_kernel<<<dim3(384), dim3(256), 0, stream>>>(pO, pSt, av);
  gemmO_kernel<<<dim3(512), dim3(256), 0, stream>>>(av, Wh + OFF_OUTW, Bf, out);
}

// Round 5
// 171.550 us; speedup vs baseline: 1.0179x; 1.0179x over previous
//
#include <hip/hip_runtime.h>

// ---------------------------------------------------------------------------
// RelativeSelfMultiheadAttn (Transformer-XL style) on gfx950.
// T=2048, B=2, D=512, NH=8, HD=64.
// Pipeline: prep -> gemm01 (QKV+R) -> attn (split-k flash) -> combine -> gemmO.
// Round-5: attn LDS-op diet (P via per-wave LDS b64/b128 instead of 16
// ds_bpermute; G scratch [ii][c] bf16 with packed b64 writes + b32-pair
// gathers; G/P overlay -> 47.6KB), scale folded into qrw/qrr, coalesced
// gemm01 epilogues for q/k/r.
// ---------------------------------------------------------------------------

typedef float f32x4 __attribute__((ext_vector_type(4)));
typedef short bf16x8 __attribute__((ext_vector_type(8)));

#define NW 1314304
#define OFF_INB  1310720
#define OFF_INW  0
#define OFF_OUTW 786432
#define OFF_POSW 1048576
// bias-buffer local offsets (floats)
#define BB_IN  0
#define BB_OUT 1536
#define BB_POS 2048
#define BB_RW  2560
#define BB_RR  3072

#define L2E 1.44269504088896340736f

__device__ __forceinline__ unsigned short f2bf(float x) {
  unsigned u = __builtin_bit_cast(unsigned, x);
  u += 0x7fffu + ((u >> 16) & 1u);   // RNE
  return (unsigned short)(u >> 16);
}
__device__ __forceinline__ float bf2f(unsigned short s) {
  return __builtin_bit_cast(float, ((unsigned)s) << 16);
}
__device__ __forceinline__ unsigned pk2(float lo, float hi) {
  return (unsigned)f2bf(lo) | ((unsigned)f2bf(hi) << 16);
}

// ---------------- prep: weight sample + activation bf16 cast ---------------
__global__ void prep_kernel(const float* __restrict__ mu, const float* __restrict__ rho,
                            const float* __restrict__ eps,
                            const float* __restrict__ input, const float* __restrict__ pos,
                            unsigned short* __restrict__ Wh, float* __restrict__ Bf,
                            unsigned short* __restrict__ inH, unsigned short* __restrict__ posH) {
  const int bx = blockIdx.x;
  if (bx < 1284) {
    int i = (bx * 256 + threadIdx.x) * 4;
    if (i < NW) {
      float4 m = *(const float4*)&mu[i];
      float4 r = *(const float4*)&rho[i];
      float4 e = *(const float4*)&eps[i];
      float w0 = m.x + ((r.x > 20.f) ? r.x : log1pf(expf(r.x))) * e.x;
      float w1 = m.y + ((r.y > 20.f) ? r.y : log1pf(expf(r.y))) * e.y;
      float w2 = m.z + ((r.z > 20.f) ? r.z : log1pf(expf(r.z))) * e.z;
      float w3 = m.w + ((r.w > 20.f) ? r.w : log1pf(expf(r.w))) * e.w;
      union { unsigned short s[4]; uint2 u; } p;
      p.s[0] = f2bf(w0); p.s[1] = f2bf(w1); p.s[2] = f2bf(w2); p.s[3] = f2bf(w3);
      *(uint2*)&Wh[i] = p.u;
      if (i >= OFF_INB) {
        float4 b; b.x = w0; b.y = w1; b.z = w2; b.w = w3;
        *(float4*)&Bf[i - OFF_INB] = b;
      }
    }
  } else if (bx < 3332) {
    int i = ((bx - 1284) * 256 + threadIdx.x) * 4;
    float4 v = *(const float4*)&input[i];
    union { unsigned short s[4]; uint2 u; } p;
    p.s[0] = f2bf(v.x); p.s[1] = f2bf(v.y); p.s[2] = f2bf(v.z); p.s[3] = f2bf(v.w);
    *(uint2*)&inH[i] = p.u;
  } else {
    int i = ((bx - 3332) * 256 + threadIdx.x) * 4;
    float4 v = *(const float4*)&pos[i];
    union { unsigned short s[4]; uint2 u; } p;
    p.s[0] = f2bf(v.x); p.s[1] = f2bf(v.y); p.s[2] = f2bf(v.z); p.s[3] = f2bf(v.w);
    *(uint2*)&posH[i] = p.u;
  }
}

// ---------------- shared 64x64x512 bf16 tile core (C = A * W^T) ------------
__device__ __forceinline__ void gemm_loop(const unsigned short* __restrict__ A,
                                          const unsigned short* __restrict__ B,
                                          unsigned short* As, unsigned short* Bs,
                                          f32x4 (&acc)[4]) {
  const int tid = threadIdx.x;
  const int wv = tid >> 6, lane = tid & 63, g = lane >> 4, cc = lane & 15;
  const int row = tid >> 2, q4 = tid & 3;
  const unsigned short* Ap = A + (size_t)row * 512 + 16 * q4;
  const unsigned short* Bp = B + (size_t)row * 512 + 16 * q4;

  *(uint4*)&As[row * 72 + 16 * q4]     = *(const uint4*)Ap;
  *(uint4*)&As[row * 72 + 16 * q4 + 8] = *(const uint4*)(Ap + 8);
  *(uint4*)&Bs[row * 72 + 16 * q4]     = *(const uint4*)Bp;
  *(uint4*)&Bs[row * 72 + 16 * q4 + 8] = *(const uint4*)(Bp + 8);
  __syncthreads();

  for (int it = 0; it < 8; it++) {
    uint4 a0, a1, b0, b1;
    const bool pf = (it < 7);
    if (pf) {
      const unsigned short* An = Ap + 64 * (it + 1);
      const unsigned short* Bn = Bp + 64 * (it + 1);
      a0 = *(const uint4*)An; a1 = *(const uint4*)(An + 8);
      b0 = *(const uint4*)Bn; b1 = *(const uint4*)(Bn + 8);
    }
    __builtin_amdgcn_s_setprio(1);
#pragma unroll
    for (int ks = 0; ks < 2; ks++) {
      bf16x8 af = *(const bf16x8*)&As[(16 * wv + cc) * 72 + 32 * ks + 8 * g];
#pragma unroll
      for (int fn = 0; fn < 4; fn++) {
        bf16x8 bf = *(const bf16x8*)&Bs[(16 * fn + cc) * 72 + 32 * ks + 8 * g];
        acc[fn] = __builtin_amdgcn_mfma_f32_16x16x32_bf16(af, bf, acc[fn], 0, 0, 0);
      }
    }
    __builtin_amdgcn_s_setprio(0);
    __syncthreads();
    if (pf) {
      *(uint4*)&As[row * 72 + 16 * q4]     = a0;
      *(uint4*)&As[row * 72 + 16 * q4 + 8] = a1;
      *(uint4*)&Bs[row * 72 + 16 * q4]     = b0;
      *(uint4*)&Bs[row * 72 + 16 * q4 + 8] = b1;
    }
    __syncthreads();
  }
}

// ---------------- gemm01: QKV projection (1536 blocks) + R proj (256) ------
// Epilogues stage the C-tile in LDS and store coalesced 16B chunks.
// qrw/qrr carry the 1/sqrt(HD)=0.125 score scale (exact bf16 exp shift).
__global__ __launch_bounds__(256, 2)
void gemm01_kernel(const unsigned short* __restrict__ inH, const unsigned short* __restrict__ posH,
                   const unsigned short* __restrict__ Wh, const float* __restrict__ Bf,
                   unsigned short* __restrict__ qrw, unsigned short* __restrict__ qrr,
                   unsigned short* __restrict__ kbuf, unsigned short* __restrict__ vT,
                   unsigned short* __restrict__ rbuf) {
  __shared__ __align__(16) unsigned short As[64 * 72];
  __shared__ __align__(16) unsigned short Bs[64 * 72];
  const int bx = blockIdx.x;
  const int tid = threadIdx.x;
  const int wv = tid >> 6, lane = tid & 63, g = lane >> 4, cc = lane & 15;

  const bool isR = (bx >= 1536);
  int m0, n0;
  const unsigned short *A, *W;
  if (!isR) {
    m0 = (bx & 63) << 6; n0 = (bx >> 6) << 6;
    A = inH + (size_t)m0 * 512;  W = Wh + OFF_INW + (size_t)n0 * 512;
  } else {
    const int t = bx - 1536;
    m0 = (t & 31) << 6; n0 = (t >> 5) << 6;
    A = posH + (size_t)m0 * 512; W = Wh + OFF_POSW + (size_t)n0 * 512;
  }

  f32x4 acc[4];
#pragma unroll
  for (int i = 0; i < 4; i++) { acc[i][0] = 0.f; acc[i][1] = 0.f; acc[i][2] = 0.f; acc[i][3] = 0.f; }
  gemm_loop(A, W, As, Bs, acc);
  // gemm_loop ends with __syncthreads(); As/Bs reusable.

  const int nh2 = (n0 >> 6) & 7;
  const int sec = isR ? 3 : (n0 >> 9);

  if (sec == 0) {
    // ---- q: stage qrw (As) and qrr (Bs), scaled by 0.125 ----
#pragma unroll
    for (int fn = 0; fn < 4; fn++) {
      const int col = n0 + 16 * fn + cc;
      const float b0 = Bf[BB_IN + col];
      const float brw = Bf[BB_RW + col], brr = Bf[BB_RR + col];
#pragma unroll
      for (int r = 0; r < 4; r++) {
        const int ml = 16 * wv + 4 * g + r;
        As[ml * 72 + 16 * fn + cc] = f2bf((acc[fn][r] + b0 + brw) * 0.125f);
        Bs[ml * 72 + 16 * fn + cc] = f2bf((acc[fn][r] + b0 + brr) * 0.125f);
      }
    }
    __syncthreads();
    const int t0 = m0 >> 1;
#pragma unroll
    for (int pass = 0; pass < 2; pass++) {
      const int ch = tid + pass * 256;
      const int bb2 = ch >> 8, tl = (ch >> 3) & 31, hc = ch & 7;
      const int ml = 2 * tl + bb2;
      uint4 v1 = *(const uint4*)&As[ml * 72 + 8 * hc];
      uint4 v2 = *(const uint4*)&Bs[ml * 72 + 8 * hc];
      const size_t dst = ((size_t)(bb2 * 8 + nh2) * 2048 + t0 + tl) * 64 + 8 * hc;
      *(uint4*)&qrw[dst] = v1;
      *(uint4*)&qrr[dst] = v2;
    }
  } else if (sec == 1) {
    // ---- k: stage into As ----
#pragma unroll
    for (int fn = 0; fn < 4; fn++) {
      const int col = n0 + 16 * fn + cc;
      const float b0 = Bf[BB_IN + col];
#pragma unroll
      for (int r = 0; r < 4; r++)
        As[(16 * wv + 4 * g + r) * 72 + 16 * fn + cc] = f2bf(acc[fn][r] + b0);
    }
    __syncthreads();
    const int t0 = m0 >> 1;
#pragma unroll
    for (int pass = 0; pass < 2; pass++) {
      const int ch = tid + pass * 256;
      const int bb2 = ch >> 8, tl = (ch >> 3) & 31, hc = ch & 7;
      const int ml = 2 * tl + bb2;
      uint4 v1 = *(const uint4*)&As[ml * 72 + 8 * hc];
      *(uint4*)&kbuf[((size_t)(bb2 * 8 + nh2) * 2048 + t0 + tl) * 64 + 8 * hc] = v1;
    }
  } else if (sec == 2) {
    // ---- v: stage, then transposed coalesced vT store ----
#pragma unroll
    for (int fn = 0; fn < 4; fn++) {
      const int col = n0 + 16 * fn + cc;
#pragma unroll
      for (int r = 0; r < 4; r++)
        As[(16 * wv + 4 * g + r) * 72 + 16 * fn + cc] = f2bf(acc[fn][r] + Bf[BB_IN + col]);
    }
    __syncthreads();
#pragma unroll
    for (int cpass = 0; cpass < 2; cpass++) {
      const int ch = tid + cpass * 256;            // 512 chunks of 8 t-values
      const int ncol = ch >> 3, bb2 = (ch >> 2) & 1, jc = ch & 3;
      union { unsigned short s[8]; uint4 u; } pk;
#pragma unroll
      for (int jj = 0; jj < 8; jj++)
        pk.s[jj] = As[(2 * (8 * jc + jj) + bb2) * 72 + ncol];
      *(uint4*)&vT[((size_t)(bb2 * 8 + nh2) * 64 + ncol) * 2048 + (m0 >> 1) + 8 * jc] = pk.u;
    }
  } else {
    // ---- r: stage into As, coalesced rbuf store ----
#pragma unroll
    for (int fn = 0; fn < 4; fn++) {
      const int col = n0 + 16 * fn + cc;
      const float b0 = Bf[BB_POS + col];
#pragma unroll
      for (int r = 0; r < 4; r++)
        As[(16 * wv + 4 * g + r) * 72 + 16 * fn + cc] = f2bf(acc[fn][r] + b0);
    }
    __syncthreads();
#pragma unroll
    for (int pass = 0; pass < 2; pass++) {
      const int ch = tid + pass * 256;
      const int ml = ch >> 3, hc = ch & 7;
      uint4 v1 = *(const uint4*)&As[ml * 72 + 8 * hc];
      *(uint4*)&rbuf[((size_t)nh2 * 2048 + m0 + ml) * 64 + 8 * hc] = v1;
    }
  }
}

// ---------------- gemmO: out projection -> f32 d_out -----------------------
__global__ __launch_bounds__(256, 2)
void gemmO_kernel(const unsigned short* __restrict__ av, const unsigned short* __restrict__ W,
                  const float* __restrict__ Bf, float* __restrict__ outp) {
  __shared__ __align__(16) unsigned short As[64 * 72];
  __shared__ __align__(16) unsigned short Bs[64 * 72];
  const int bx = blockIdx.x;
  const int tid = threadIdx.x;
  const int wv = tid >> 6, lane = tid & 63, g = lane >> 4, cc = lane & 15;
  const int m0 = (bx & 63) << 6, n0 = (bx >> 6) << 6;

  f32x4 acc[4];
#pragma unroll
  for (int i = 0; i < 4; i++) { acc[i][0] = 0.f; acc[i][1] = 0.f; acc[i][2] = 0.f; acc[i][3] = 0.f; }
  gemm_loop(av + (size_t)m0 * 512, W + (size_t)n0 * 512, As, Bs, acc);

#pragma unroll
  for (int fn = 0; fn < 4; fn++) {
    const int col = n0 + 16 * fn + cc;
#pragma unroll
    for (int r = 0; r < 4; r++) {
      const int mrow = m0 + 16 * wv + 4 * g + r;
      outp[(size_t)mrow * 512 + col] = acc[fn][r] + Bf[BB_OUT + col];
    }
  }
}

// ---------------- split-k fused relative flash attention -------------------
// 1280 blocks; bn = bx&15, sid = 79-(bx>>4) (big chunks first). Chunks of
// <=8 k-tiles. 3 blocks/CU (47.6KB LDS). Scores pre-scaled via qrw/qrr.
// Softmax lane-local (swapped St=K*Q^T); BD band-GEMM, G scratch [ii][c]
// bf16 per-wave; P redistributed through per-wave LDS (overlaid on G).
__global__ __launch_bounds__(256, 3)
void attn_kernel(const unsigned short* __restrict__ qrw, const unsigned short* __restrict__ qrr,
                 const unsigned short* __restrict__ kb, const unsigned short* __restrict__ vt,
                 const unsigned short* __restrict__ rb, unsigned short* __restrict__ av,
                 unsigned short* __restrict__ pO, float* __restrict__ pStats)
{
  __shared__ __align__(16) unsigned short Ks[64 * 72];
  __shared__ __align__(16) unsigned short Vs[64 * 72];
  __shared__ __align__(16) unsigned short Rs[128 * 72];    // ring: slot = u & 127
  __shared__ __align__(16) unsigned short GPs[4 * 16 * 84]; // per-wave G [16][84] / P [16][72] overlay

  const int tid = threadIdx.x;
  const int wv = tid >> 6, lane = tid & 63, g = lane >> 4, cc = lane & 15;
  const int bx = (int)blockIdx.x;
  const int bn = bx & 15;
  const int sid = 79 - (bx >> 4);
  int qt, s, ns;
  if (sid < 8)       { qt = sid;                s = 0;           ns = 1; }
  else if (sid < 24) { qt = 8 + ((sid - 8) >> 1); s = (sid - 8) & 1; ns = 2; }
  else if (sid < 48) { const int t = sid - 24; const int q3 = t / 3; qt = 16 + q3; s = t - 3 * q3; ns = 3; }
  else               { const int t = sid - 48; qt = 24 + (t >> 2); s = t & 3; ns = 4; }
  const int kt0 = s * 8;
  const int kt1 = (kt0 + 8 < qt + 1) ? (kt0 + 8) : (qt + 1);

  const int nh = bn & 7, bb = bn >> 3;
  const int i0 = qt * 64;
  const int i0g = i0 + wv * 16;
  const int w0base = 1984 - i0;                // R window base at kt=0

  const size_t qko = (size_t)bn * 2048 * 64;
  const size_t ro = (size_t)nh * 2048 * 64;

  // hoisted Q fragments (B-operand: lane holds Q[i0g+cc][d-slice])
  bf16x8 qw[2], qr[2];
#pragma unroll
  for (int ks = 0; ks < 2; ks++) {
    qw[ks] = *(const bf16x8*)&qrw[qko + (size_t)(i0g + cc) * 64 + 32 * ks + 8 * g];
    qr[ks] = *(const bf16x8*)&qrr[qko + (size_t)(i0g + cc) * 64 + 32 * ks + 8 * g];
  }

  float m_run = -3.0e38f, l_run = 0.f;
  f32x4 o[4];
#pragma unroll
  for (int i = 0; i < 4; i++) { o[i][0] = 0.f; o[i][1] = 0.f; o[i][2] = 0.f; o[i][3] = 0.f; }

  const int srow = tid >> 2, sq = tid & 3;     // staging: 4 thr/row, 16 shorts
  const int rrow = tid >> 1, rhalf = tid & 1;  // R prologue: 2 thr/row, 32 shorts
  unsigned short* Gw = &GPs[wv * 1344];
  const int rbase = 48 - 16 * wv;

  // ---- prologue: stage kt0 K/V tile + 128-row R window ----
  {
    const unsigned short* kp = &kb[qko + (size_t)(kt0 * 64 + srow) * 64 + 16 * sq];
    *(uint4*)&Ks[srow * 72 + 16 * sq]     = *(const uint4*)kp;
    *(uint4*)&Ks[srow * 72 + 16 * sq + 8] = *(const uint4*)(kp + 8);
    const unsigned short* vp = &vt[qko + (size_t)srow * 2048 + kt0 * 64 + 16 * sq];
    *(uint4*)&Vs[srow * 72 + 16 * sq]     = *(const uint4*)vp;
    *(uint4*)&Vs[srow * 72 + 16 * sq + 8] = *(const uint4*)(vp + 8);
    const int u0 = w0base + kt0 * 64 + rrow;
    const int uc0 = u0 > 2047 ? 2047 : u0;     // clamped rows only feed masked entries
    const unsigned short* rp = &rb[ro + (size_t)uc0 * 64 + 32 * rhalf];
    unsigned short* rd = &Rs[(u0 & 127) * 72 + 32 * rhalf];
    *(uint4*)rd        = *(const uint4*)rp;
    *(uint4*)(rd + 8)  = *(const uint4*)(rp + 8);
    *(uint4*)(rd + 16) = *(const uint4*)(rp + 16);
    *(uint4*)(rd + 24) = *(const uint4*)(rp + 24);
  }
  __syncthreads();

  for (int kt = kt0; kt < kt1; kt++) {
    const int j0 = kt * 64;
    const int w0k = w0base + j0;
    const bool pf = (kt + 1 < kt1);

    // ---- T14: issue next-tile loads into regs ----
    uint4 ka0, ka1, va0, va1, ra0, ra1;
    int rslot = 0;
    if (pf) {
      const unsigned short* kp = &kb[qko + (size_t)(j0 + 64 + srow) * 64 + 16 * sq];
      ka0 = *(const uint4*)kp; ka1 = *(const uint4*)(kp + 8);
      const unsigned short* vp = &vt[qko + (size_t)srow * 2048 + j0 + 64 + 16 * sq];
      va0 = *(const uint4*)vp; va1 = *(const uint4*)(vp + 8);
      const int unew = w0k + 128 + (tid >> 2);  // 64 new ring rows
      rslot = unew & 127;
      const int uc = unew > 2047 ? 2047 : unew;
      const unsigned short* rp = &rb[ro + (size_t)uc * 64 + 16 * sq];
      ra0 = *(const uint4*)rp; ra1 = *(const uint4*)(rp + 8);
    }

    // ---- St[jj,ii] = sum_d K[j0+jj,d] * Qrw[i0g+ii,d] (pre-scaled) ----
    f32x4 st[4];
#pragma unroll
    for (int i = 0; i < 4; i++) { st[i][0] = 0.f; st[i][1] = 0.f; st[i][2] = 0.f; st[i][3] = 0.f; }
    __builtin_amdgcn_s_setprio(1);
#pragma unroll
    for (int ks = 0; ks < 2; ks++) {
#pragma unroll
      for (int fm = 0; fm < 4; fm++) {
        bf16x8 ka = *(const bf16x8*)&Ks[(16 * fm + cc) * 72 + 32 * ks + 8 * g];
        st[fm] = __builtin_amdgcn_mfma_f32_16x16x32_bf16(ka, qw[ks], st[fm], 0, 0, 0);
      }
    }
    // ---- G[c,ii] = sum_d R[ring(w0k+rbase+c),d] * Qrr[i0g+ii,d] ----
    f32x4 gt[5];
#pragma unroll
    for (int i = 0; i < 5; i++) { gt[i][0] = 0.f; gt[i][1] = 0.f; gt[i][2] = 0.f; gt[i][3] = 0.f; }
    const int rr0 = w0k + rbase + cc;
#pragma unroll
    for (int ks = 0; ks < 2; ks++) {
#pragma unroll
      for (int fm = 0; fm < 5; fm++) {
        const int rrw = (rr0 + 16 * fm) & 127;
        bf16x8 ra = *(const bf16x8*)&Rs[rrw * 72 + 32 * ks + 8 * g];
        gt[fm] = __builtin_amdgcn_mfma_f32_16x16x32_bf16(ra, qr[ks], gt[fm], 0, 0, 0);
      }
    }
    __builtin_amdgcn_s_setprio(0);

    // ---- G scratch write: [ii=cc][c] bf16, packed b64 per fm ----
#pragma unroll
    for (int fm = 0; fm < 5; fm++) {
      uint2 w;
      w.x = pk2(gt[fm][0], gt[fm][1]);
      w.y = pk2(gt[fm][2], gt[fm][3]);
      *(uint2*)&Gw[cc * 84 + 16 * fm + 4 * g] = w;
    }

    // ---- combine + mask + online softmax (state at query ii == cc) ----
    float p[4][4];
    float tm = -3.0e38f;
    const bool diag = (kt == qt);
    const int c00 = 15 - cc + 4 * g;
#pragma unroll
    for (int fm = 0; fm < 4; fm++) {
      const int c0 = c00 + 16 * fm;
      const int e0 = c0 & ~1;
      const unsigned short* gp = &Gw[cc * 84 + e0];
      unsigned d0 = *(const unsigned*)gp;
      unsigned d1 = *(const unsigned*)(gp + 2);
      unsigned d2 = *(const unsigned*)(gp + 4);
      unsigned lo01, lo23;
      if (c0 & 1) { lo01 = (d0 >> 16) | (d1 << 16); lo23 = (d1 >> 16) | (d2 << 16); }
      else        { lo01 = d0; lo23 = d1; }
      float bd0 = bf2f((unsigned short)(lo01 & 0xffffu));
      float bd1 = bf2f((unsigned short)(lo01 >> 16));
      float bd2 = bf2f((unsigned short)(lo23 & 0xffffu));
      float bd3 = bf2f((unsigned short)(lo23 >> 16));
      float sv0 = st[fm][0] + bd0;
      float sv1 = st[fm][1] + bd1;
      float sv2 = st[fm][2] + bd2;
      float sv3 = st[fm][3] + bd3;
      if (diag) {
        const int jj = 16 * fm + 4 * g;
        const int lim = cc + 16 * wv;
        if (jj + 0 > lim) sv0 = -3.0e38f;
        if (jj + 1 > lim) sv1 = -3.0e38f;
        if (jj + 2 > lim) sv2 = -3.0e38f;
        if (jj + 3 > lim) sv3 = -3.0e38f;
      }
      p[fm][0] = sv0; p[fm][1] = sv1; p[fm][2] = sv2; p[fm][3] = sv3;
      tm = fmaxf(tm, fmaxf(fmaxf(sv0, sv1), fmaxf(sv2, sv3)));
    }
    tm = fmaxf(tm, __shfl_xor(tm, 16));
    tm = fmaxf(tm, __shfl_xor(tm, 32));
    const float m_new = fmaxf(m_run, tm);
    const float sc = exp2f((m_run - m_new) * L2E);
    float ps = 0.f;
#pragma unroll
    for (int fm = 0; fm < 4; fm++)
#pragma unroll
      for (int r = 0; r < 4; r++) {
        float pv = exp2f((p[fm][r] - m_new) * L2E);
        p[fm][r] = pv;
        ps += pv;
      }
    ps += __shfl_xor(ps, 16);
    ps += __shfl_xor(ps, 32);
    l_run = l_run * sc + ps;
    m_run = m_new;

    // rescale O (O rows are ii = 4g+r; state at lane ii)
    float scr[4];
#pragma unroll
    for (int r = 0; r < 4; r++) scr[r] = __shfl(sc, 4 * g + r);
#pragma unroll
    for (int fn = 0; fn < 4; fn++)
#pragma unroll
      for (int r = 0; r < 4; r++) o[fn][r] *= scr[r];

    // ---- P -> per-wave LDS (overlay on G; G fully consumed above) ----
#pragma unroll
    for (int fm = 0; fm < 4; fm++) {
      uint2 w;
      w.x = pk2(p[fm][0], p[fm][1]);
      w.y = pk2(p[fm][2], p[fm][3]);
      *(uint2*)&Gw[cc * 72 + 16 * fm + 4 * g] = w;   // P[ii=cc][jj=16fm+4g+r]
    }
    bf16x8 pa[2];
#pragma unroll
    for (int ks = 0; ks < 2; ks++)
      pa[ks] = *(const bf16x8*)&Gw[cc * 72 + 32 * ks + 8 * g];  // P[cc][32ks+8g..+7]

    // ---- O[ii,hd] += P[ii,jj] * V[j0+jj,hd] ----
    __builtin_amdgcn_s_setprio(1);
#pragma unroll
    for (int ks = 0; ks < 2; ks++) {
#pragma unroll
      for (int fn = 0; fn < 4; fn++) {
        bf16x8 vb = *(const bf16x8*)&Vs[(16 * fn + cc) * 72 + 32 * ks + 8 * g];
        o[fn] = __builtin_amdgcn_mfma_f32_16x16x32_bf16(pa[ks], vb, o[fn], 0, 0, 0);
      }
    }
    __builtin_amdgcn_s_setprio(0);

    __syncthreads();           // all waves done reading Ks/Vs/Rs
    if (pf) {
      *(uint4*)&Ks[srow * 72 + 16 * sq]     = ka0;
      *(uint4*)&Ks[srow * 72 + 16 * sq + 8] = ka1;
      *(uint4*)&Vs[srow * 72 + 16 * sq]     = va0;
      *(uint4*)&Vs[srow * 72 + 16 * sq + 8] = va1;
      unsigned short* rd = &Rs[rslot * 72 + 16 * sq];
      *(uint4*)rd       = ra0;
      *(uint4*)(rd + 8) = ra1;
    }
    __syncthreads();           // next tiles ready
  }

  if (ns == 1) {
    // ---- direct: normalize and store attn_vec[t][b][n][hd] (bf16) ----
    const float inv = 1.0f / l_run;
    float invr[4];
#pragma unroll
    for (int r = 0; r < 4; r++) invr[r] = __shfl(inv, 4 * g + r);
#pragma unroll
    for (int fn = 0; fn < 4; fn++) {
      const int hd = 16 * fn + cc;
#pragma unroll
      for (int r = 0; r < 4; r++) {
        const int irow = i0g + 4 * g + r;
        av[((size_t)(irow * 2 + bb) * 8 + nh) * 64 + hd] = f2bf(o[fn][r] * invr[r]);
      }
    }
  } else {
    // ---- partial: unnormalized O (bf16) + per-row (m,l) ----
    const size_t slot = (size_t)(bn * 80 + sid);
#pragma unroll
    for (int fn = 0; fn < 4; fn++) {
      const int hd = 16 * fn + cc;
#pragma unroll
      for (int r = 0; r < 4; r++)
        pO[slot * 4096 + (16 * wv + 4 * g + r) * 64 + hd] = f2bf(o[fn][r]);
    }
    if (g == 0) {
      pStats[slot * 128 + (16 * wv + cc) * 2]     = m_run;
      pStats[slot * 128 + (16 * wv + cc) * 2 + 1] = l_run;
    }
  }
}

// ---------------- combine: merge split-k partials (qt >= 8) ----------------
__global__ __launch_bounds__(256)
void combine_kernel(const unsigned short* __restrict__ pO, const float* __restrict__ pStats,
                    unsigned short* __restrict__ av) {
  const int bxx = (int)blockIdx.x;       // 16 bn x 24 qt
  const int bn = bxx & 15, qt = 8 + (bxx >> 4);
  const int nh = bn & 7, bb = bn >> 3;
  const int ns = (qt >> 3) + 1;
  const int sid0 = (qt < 16) ? (8 + (qt - 8) * 2)
                 : (qt < 24) ? (24 + (qt - 16) * 3)
                             : (48 + (qt - 24) * 4);
  const int tid = threadIdx.x;
  const int ql = tid >> 2, hq = tid & 3;
  const size_t sb = (size_t)(bn * 80 + sid0);

  float M = -3.0e38f;
  for (int i = 0; i < ns; i++)
    M = fmaxf(M, pStats[(sb + i) * 128 + ql * 2]);

  float L = 0.f;
  float accv[16];
#pragma unroll
  for (int j = 0; j < 16; j++) accv[j] = 0.f;
  for (int i = 0; i < ns; i++) {
    const float mi = pStats[(sb + i) * 128 + ql * 2];
    const float li = pStats[(sb + i) * 128 + ql * 2 + 1];
    const float w = exp2f((mi - M) * L2E);
    L += w * li;
    union { uint4 u; unsigned short s[8]; } c0, c1;
    const unsigned short* src = &pO[(sb + i) * 4096 + ql * 64 + 16 * hq];
    c0.u = *(const uint4*)src;
    c1.u = *(const uint4*)(src + 8);
#pragma unroll
    for (int j = 0; j < 8; j++) accv[j]     += w * bf2f(c0.s[j]);
#pragma unroll
    for (int j = 0; j < 8; j++) accv[8 + j] += w * bf2f(c1.s[j]);
  }
  const float inv = 1.0f / L;
  union { uint4 u; unsigned short s[8]; } o0, o1;
#pragma unroll
  for (int j = 0; j < 8; j++) o0.s[j] = f2bf(accv[j] * inv);
#pragma unroll
  for (int j = 0; j < 8; j++) o1.s[j] = f2bf(accv[8 + j] * inv);
  const int q = qt * 64 + ql;
  unsigned short* dst = &av[((size_t)(q * 2 + bb) * 8 + nh) * 64 + 16 * hq];
  *(uint4*)dst       = o0.u;
  *(uint4*)(dst + 8) = o1.u;
}

// ---------------------------------------------------------------------------
extern "C" void kernel_launch(void* const* d_in, const int* in_sizes, int n_in,
                              void* d_out, int out_size, void* d_ws, size_t ws_size,
                              hipStream_t stream) {
  const float* input = (const float*)d_in[0];
  const float* pos   = (const float*)d_in[1];
  // d_in[2] attn_mask: known causal triu(1), not read
  const float* mu  = (const float*)d_in[3];
  const float* rho = (const float*)d_in[4];
  const float* eps = (const float*)d_in[5];
  float* out = (float*)d_out;

  // workspace layout (bytes); total ~39 MB. av aliases inH (dead after gemm01).
  char* ws = (char*)d_ws;
  unsigned short* Wh   = (unsigned short*)ws;                 // 2,628,608
  float*          Bf   = (float*)(ws + 2628608);              // 14,336
  unsigned short* inH  = (unsigned short*)(ws + 2642944);     // 4,194,304
  unsigned short* posH = (unsigned short*)(ws + 6837248);     // 2,097,152
  unsigned short* qrw  = (unsigned short*)(ws + 8934400);     // 4 MB each
  unsigned short* qrr  = (unsigned short*)(ws + 13128704);
  unsigned short* kbuf = (unsigned short*)(ws + 17323008);
  unsigned short* vT   = (unsigned short*)(ws + 21517312);
  unsigned short* rbuf = (unsigned short*)(ws + 25711616);    // 2,097,152
  unsigned short* pO   = (unsigned short*)(ws + 27808768);    // 10,485,760
  float*          pSt  = (float*)(ws + 38294528);             // 655,360
  unsigned short* av   = inH;                                 // alias

  prep_kernel<<<dim3(4356), dim3(256), 0, stream>>>(mu, rho, eps, input, pos, Wh, Bf, inH, posH);
  gemm01_kernel<<<dim3(1792), dim3(256), 0, stream>>>(inH, posH, Wh, Bf, qrw, qrr, kbuf, vT, rbuf);
  attn_kernel<<<dim3(1280), dim3(256), 0, stream>>>(qrw, qrr, kbuf, vT, rbuf, av, pO, pSt);
  combine_kernel<<<dim3(384), dim3(256), 0, stream>>>(pO, pSt, av);
  gemmO_kernel<<<dim3(512), dim3(256), 0, stream>>>(av, Wh + OFF_OUTW, Bf, out);
}